// Round 5
// baseline (1289.708 us; speedup 1.0000x reference)
//
#include <hip/hip_runtime.h>
#include <math.h>

namespace {

constexpr int TSEQ   = 2048;
constexpr int DIN    = 16;
constexpr int NH1    = 5;
constexpr int NH2    = 50;
constexpr int NCLS   = 20;
constexpr int CHUNK  = 64;
constexpr int NCHUNK = TSEQ / CHUNK;
constexpr int BATCH  = 256;

// No clamp: exp(+inf)->inf, rcp(inf)->0 — still correct; inputs bounded.
__device__ __forceinline__ float fast_sigm(float x) {
    return __fdividef(1.f, 1.f + __expf(-x));
}
// tanh(x) = 2*sigm(2x) - 1
__device__ __forceinline__ float fast_tanh(float x) {
    return fmaf(2.f, fast_sigm(2.f * x), -1.f);
}

// quad_perm DPP: VALU-speed cross-lane within aligned quads.
template <int CTRL>
__device__ __forceinline__ float qperm(float v) {
    int i = __builtin_bit_cast(int, v);
    int r = __builtin_amdgcn_update_dpp(i, i, CTRL, 0xf, 0xf, false);
    return __builtin_bit_cast(float, r);
}
__device__ __forceinline__ float rdlane(float v, int lane) {
    return __builtin_bit_cast(float,
        __builtin_amdgcn_readlane(__builtin_bit_cast(int, v), lane));
}

// Wave-4-only barrier: LDS-drain + s_barrier, NO vmcnt drain, so wave 4's
// global x prefetch stays in flight across the 2048 step barriers.
// L2 waves use plain __syncthreads(). Barrier COUNTS match across roles.
#define W4_BARRIER() asm volatile("s_waitcnt lgkmcnt(0)\n\ts_barrier" ::: "memory")

// One block = 5 waves = one batch element.
// R5: split-M full-K L2. Waves 0-3 each own COMPLETE units (all 4 gates,
// K=50): {13,13,12,12} units at offsets {0,13,26,38}. Per step the ONLY
// cross-wave exchange is h2 itself: g==0 lanes write 13 floats, barrier,
// all waves broadcast-read all 50 into VGPRs (uniform-address ds_read_b128,
// conflict-free). This removes the R1-R4 partial exchange (4-way-conflicted
// ds_write_b128 + gather + add tree + 15 readlanes) from the serial chain.
// Wave 4: L1 producer + x stager, one chunk ahead (unchanged).
__global__ __launch_bounds__(320, 1) void lstm_fused_kernel(
    const float* __restrict__ x,     // (256,2048,16)
    const float* __restrict__ W1ih,  // (20,16)
    const float* __restrict__ W1hh,  // (20,5)
    const float* __restrict__ b1ih,  // (20)
    const float* __restrict__ b1hh,  // (20)
    const float* __restrict__ W2ih,  // (200,5)
    const float* __restrict__ W2hh,  // (200,50)
    const float* __restrict__ b2ih,  // (200)
    const float* __restrict__ b2hh,  // (200)
    const float* __restrict__ Wfc,   // (20,50)
    const float* __restrict__ bfc,   // (20)
    float* __restrict__ out)         // result(256,20) ++ last(256,50)
{
    const int b    = blockIdx.x;
    const int tid  = threadIdx.x;
    const int lane = tid & 63;
    const int wv   = tid >> 6;

    __shared__ __align__(16) float s_x[2][CHUNK * DIN];   // x dbuf (8 KB)
    __shared__ __align__(16) float s_h1[2][CHUNK][8];     // h1 stream dbuf (4 KB)
    __shared__ __align__(16) float s_h2x[2][64];          // h2 exchange dbuf (512 B)

    const float* xb = x + (size_t)b * TSEQ * DIN;

    if (wv == 4) {
        // ================= wave 4: L1 producer + x stager =================
        const int r1 = (lane < NCLS) ? ((lane & 3) * NH1 + (lane >> 2)) : 0;
        float w1h[NH1], w1x[DIN];
        #pragma unroll
        for (int j = 0; j < NH1; ++j) w1h[j] = W1hh[r1 * NH1 + j];
        #pragma unroll
        for (int d = 0; d < DIN; ++d) w1x[d] = W1ih[r1 * DIN + d];
        const float bias1 = b1ih[r1] + b1hh[r1];
        const bool  isg1  = ((lane & 3) == 2) && (lane < NCLS);
        const float isc1  = isg1 ? 2.f : 1.f;
        const float osc1  = isg1 ? 2.f : 1.f;
        const float off1  = isg1 ? -1.f : 0.f;
        float c1 = 0.f;
        float sh0v = 0.f, sh1v = 0.f, sh2v = 0.f, sh3v = 0.f, sh4v = 0.f;
        float4 xr0, xr1, xr2, xr3;

        auto l1_prod = [&](const float* xs, float* h1out) {
            float4 xv0 = *(const float4*)(xs + 0);
            float4 xv1 = *(const float4*)(xs + 4);
            float4 xv2 = *(const float4*)(xs + 8);
            float4 xv3 = *(const float4*)(xs + 12);
            float sa = fmaf(xv0.y, w1x[1],  xv0.x * w1x[0]);
            sa = fmaf(xv0.z, w1x[2], sa);  sa = fmaf(xv0.w, w1x[3], sa);
            float sb = fmaf(xv1.y, w1x[5],  xv1.x * w1x[4]);
            sb = fmaf(xv1.z, w1x[6], sb);  sb = fmaf(xv1.w, w1x[7], sb);
            float sc = fmaf(xv2.y, w1x[9],  xv2.x * w1x[8]);
            sc = fmaf(xv2.z, w1x[10], sc); sc = fmaf(xv2.w, w1x[11], sc);
            float sd = fmaf(xv3.y, w1x[13], xv3.x * w1x[12]);
            sd = fmaf(xv3.z, w1x[14], sd); sd = fmaf(xv3.w, w1x[15], sd);
            float ha = fmaf(sh1v, w1h[1], sh0v * w1h[0]);
            ha = fmaf(sh2v, w1h[2], ha);
            float hb = fmaf(sh4v, w1h[4], sh3v * w1h[3]);
            float g1 = ((sa + sb) + (sc + sd)) + ((ha + hb) + bias1);
            float act = fmaf(osc1, fast_sigm(isc1 * g1), off1);
            float f_ = qperm<0xB1>(act);
            float gg = qperm<0x4E>(act);
            float o_ = qperm<0x1B>(act);
            c1 = fmaf(f_, c1, act * gg);            // valid on lanes 4j+0
            float h1me = o_ * fast_tanh(c1);
            sh0v = rdlane(h1me, 0);  sh1v = rdlane(h1me, 4);
            sh2v = rdlane(h1me, 8);  sh3v = rdlane(h1me, 12);
            sh4v = rdlane(h1me, 16);
            if ((lane & 3) == 0 && lane < NCLS) h1out[lane >> 2] = h1me;
        };

        // prologue: stage chunk0, run L1 chunk0, stage chunk1, preload chunk2
        xr0 = ((const float4*)(xb))[lane];
        xr1 = ((const float4*)(xb + 256))[lane];
        xr2 = ((const float4*)(xb + 512))[lane];
        xr3 = ((const float4*)(xb + 768))[lane];
        ((float4*)s_x[0])[lane]       = xr0;
        ((float4*)s_x[0])[64 + lane]  = xr1;
        ((float4*)s_x[0])[128 + lane] = xr2;
        ((float4*)s_x[0])[192 + lane] = xr3;
        for (int t = 0; t < CHUNK; ++t)
            l1_prod(&s_x[0][t * DIN], &s_h1[0][t][0]);
        xr0 = ((const float4*)(xb + 1024))[lane];
        xr1 = ((const float4*)(xb + 1280))[lane];
        xr2 = ((const float4*)(xb + 1536))[lane];
        xr3 = ((const float4*)(xb + 1792))[lane];
        ((float4*)s_x[1])[lane]       = xr0;
        ((float4*)s_x[1])[64 + lane]  = xr1;
        ((float4*)s_x[1])[128 + lane] = xr2;
        ((float4*)s_x[1])[192 + lane] = xr3;
        xr0 = ((const float4*)(xb + 2048))[lane];
        xr1 = ((const float4*)(xb + 2304))[lane];
        xr2 = ((const float4*)(xb + 2560))[lane];
        xr3 = ((const float4*)(xb + 2816))[lane];
        W4_BARRIER();                                   // barrier #1

        #pragma unroll 1
        for (int t = 0; t < TSEQ; ++t) {
            const int tt = t & (CHUNK - 1);
            const int c  = t >> 6;
            if (tt == 0 && c + 2 < NCHUNK) {
                // land staged x (chunk c+2) into s_x[c&1]; kick loads for c+3
                ((float4*)s_x[c & 1])[lane]       = xr0;
                ((float4*)s_x[c & 1])[64 + lane]  = xr1;
                ((float4*)s_x[c & 1])[128 + lane] = xr2;
                ((float4*)s_x[c & 1])[192 + lane] = xr3;
                if (c + 3 < NCHUNK) {
                    const float* xc = xb + (size_t)(c + 3) * (CHUNK * DIN);
                    xr0 = ((const float4*)(xc))[lane];
                    xr1 = ((const float4*)(xc + 256))[lane];
                    xr2 = ((const float4*)(xc + 512))[lane];
                    xr3 = ((const float4*)(xc + 768))[lane];
                }
            }
            if (c + 1 < NCHUNK)
                l1_prod(&s_x[(c & 1) ^ 1][tt * DIN], &s_h1[(c & 1) ^ 1][tt][0]);
            W4_BARRIER();
        }
    } else {
        // ================= waves 0-3: split-M full-K L2 ==================
        const int  ul   = lane >> 2;
        const int  g    = lane & 3;
        const int  uoff = (wv < 3) ? 13 * wv : 38;      // {0,13,26,38}
        const int  ucnt = (wv < 2) ? 13 : 12;           // {13,13,12,12}
        const bool on   = (ul < ucnt);
        const int  u    = uoff + (on ? ul : 0);
        const int  rr   = g * NH2 + u;                  // my gate row

        float w2h[NH2];                                 // full-K recurrent weights
        #pragma unroll
        for (int k = 0; k < NH2; ++k) w2h[k] = on ? W2hh[rr * NH2 + k] : 0.f;
        float w2i[NH1];
        float bias2 = 0.f;
        if (on) {
            #pragma unroll
            for (int d = 0; d < NH1; ++d) w2i[d] = W2ih[rr * NH1 + d];
            bias2 = b2ih[rr] + b2hh[rr];
        } else {
            #pragma unroll
            for (int d = 0; d < NH1; ++d) w2i[d] = 0.f;
        }
        const bool  isg2 = (g == 2);
        const float isc2 = isg2 ? 2.f : 1.f;
        const float osc2 = isg2 ? 2.f : 1.f;
        const float off2 = isg2 ? -1.f : 0.f;

        float c2 = 0.f;
        if (wv == 0) { s_h2x[0][lane] = 0.f; s_h2x[1][lane] = 0.f; }
        __syncthreads();                                // barrier #1

        // prefetch h1(t=0) into carried regs (off the critical chain)
        float4 h1r4 = *(const float4*)&s_h1[0][0][0];
        float  h1r1 = s_h1[0][0][4];

        #pragma unroll 1
        for (int t = 0; t < TSEQ; ++t) {
            const int rsl = (t + 1) & 1;                // h2(t-1) slot
            const int wsl = t & 1;                      // h2(t) slot

            // issue h2 broadcast reads first (uniform addr -> conflict-free)
            const float4* hbp = (const float4*)&s_h2x[rsl][0];
            const float4 hb0 = hbp[0],  hb1 = hbp[1],  hb2 = hbp[2];
            const float4 hb3 = hbp[3],  hb4 = hbp[4],  hb5 = hbp[5];
            const float4 hb6 = hbp[6],  hb7 = hbp[7],  hb8 = hbp[8];
            const float4 hb9 = hbp[9],  hb10 = hbp[10], hb11 = hbp[11];
            const float2 hbt = *(const float2*)&s_h2x[rsl][48];

            // x-side gate from h1 regs carried since LAST interval (data long
            // arrived; 6 VALU ops run under the hb read latency)
            float xq = fmaf(h1r4.x, w2i[0], bias2);
            xq = fmaf(h1r4.y, w2i[1], xq);
            xq = fmaf(h1r4.z, w2i[2], xq);
            xq = fmaf(h1r4.w, w2i[3], xq);
            xq = fmaf(h1r1,  w2i[4], xq);

            // issue h1 reads for t+1 (latency spans the whole chain + barrier)
            {
                const int tn = (t + 1) & (TSEQ - 1);    // t=2047: stale, unused
                const int sl = (tn >> 6) & 1, ix = tn & (CHUNK - 1);
                h1r4 = *(const float4*)&s_h1[sl][ix][0];
                h1r1 = s_h1[sl][ix][4];
            }

            // full-K matvec: 4-way ILP, k ascending per accumulator
            float a0 = 0.f, a1 = 0.f, a2 = 0.f, a3 = 0.f;
            #define HBF(J, HB)                                   \
                a0 = fmaf(HB.x, w2h[4 * J + 0], a0);             \
                a1 = fmaf(HB.y, w2h[4 * J + 1], a1);             \
                a2 = fmaf(HB.z, w2h[4 * J + 2], a2);             \
                a3 = fmaf(HB.w, w2h[4 * J + 3], a3);
            HBF(0, hb0)  HBF(1, hb1)  HBF(2, hb2)  HBF(3, hb3)
            HBF(4, hb4)  HBF(5, hb5)  HBF(6, hb6)  HBF(7, hb7)
            HBF(8, hb8)  HBF(9, hb9)  HBF(10, hb10) HBF(11, hb11)
            #undef HBF
            a0 = fmaf(hbt.x, w2h[48], a0);
            a1 = fmaf(hbt.y, w2h[49], a1);

            float pre  = ((a0 + a1) + (a2 + a3)) + xq;
            float act2 = fmaf(osc2, fast_sigm(isc2 * pre), off2);
            float v1 = qperm<0xB1>(act2);
            float v2 = qperm<0x4E>(act2);
            float v3 = qperm<0x1B>(act2);
            c2 = fmaf(v1, c2, act2 * v2);               // valid on g==0 lanes
            float hn = v3 * fast_tanh(c2);
            if (g == 0 && on) s_h2x[wsl][u] = hn;
            __syncthreads();
        }
    }

    __syncthreads();                                    // join (count-matched)
    // ---- outputs: result(256,20) @0, last(256,50) @5120 ----
    // final h2 = step 2047 -> slot 1
    if (tid < NH2) out[BATCH * NCLS + b * NH2 + tid] = s_h2x[1][tid];
    if (tid < NCLS) {
        float acc = bfc[tid];
        const float* wr = Wfc + tid * NH2;
        #pragma unroll
        for (int j = 0; j < NH2; ++j) acc = fmaf(s_h2x[1][j], wr[j], acc);
        out[b * NCLS + tid] = acc;
    }
}

} // namespace

extern "C" void kernel_launch(void* const* d_in, const int* in_sizes, int n_in,
                              void* d_out, int out_size, void* d_ws, size_t ws_size,
                              hipStream_t stream) {
    (void)in_sizes; (void)n_in; (void)d_ws; (void)ws_size; (void)out_size;
    const float* x    = (const float*)d_in[0];
    const float* W1ih = (const float*)d_in[1];
    const float* W1hh = (const float*)d_in[2];
    const float* b1ih = (const float*)d_in[3];
    const float* b1hh = (const float*)d_in[4];
    const float* W2ih = (const float*)d_in[5];
    const float* W2hh = (const float*)d_in[6];
    const float* b2ih = (const float*)d_in[7];
    const float* b2hh = (const float*)d_in[8];
    const float* Wfc  = (const float*)d_in[9];
    const float* bfc  = (const float*)d_in[10];

    lstm_fused_kernel<<<dim3(BATCH), dim3(320), 0, stream>>>(
        x, W1ih, W1hh, b1ih, b1hh, W2ih, W2hh, b2ih, b2hh, Wfc, bfc,
        (float*)d_out);
}

// Round 6
// 1032.971 us; speedup vs baseline: 1.2485x; 1.2485x over previous
//
#include <hip/hip_runtime.h>
#include <math.h>

namespace {

constexpr int TSEQ   = 2048;
constexpr int DIN    = 16;
constexpr int NH1    = 5;
constexpr int NH2    = 50;
constexpr int NCLS   = 20;
constexpr int CHUNK  = 64;
constexpr int NCHUNK = TSEQ / CHUNK;
constexpr int BATCH  = 256;

// No clamp: exp(+inf)->inf, rcp(inf)->0 — still correct; inputs bounded.
__device__ __forceinline__ float fast_sigm(float x) {
    return __fdividef(1.f, 1.f + __expf(-x));
}
// tanh(x) = 2*sigm(2x) - 1
__device__ __forceinline__ float fast_tanh(float x) {
    return fmaf(2.f, fast_sigm(2.f * x), -1.f);
}

// quad_perm DPP: VALU-speed cross-lane within aligned quads.
template <int CTRL>
__device__ __forceinline__ float qperm(float v) {
    int i = __builtin_bit_cast(int, v);
    int r = __builtin_amdgcn_update_dpp(i, i, CTRL, 0xf, 0xf, false);
    return __builtin_bit_cast(float, r);
}
__device__ __forceinline__ float rdlane(float v, int lane) {
    return __builtin_bit_cast(float,
        __builtin_amdgcn_readlane(__builtin_bit_cast(int, v), lane));
}

// Wave-4-only barrier: LDS-drain + s_barrier, NO vmcnt drain, so wave 4's
// global x prefetch stays in flight across the 2048 step barriers.
// L2 waves use plain __syncthreads(). Barrier COUNTS match across roles.
#define W4_BARRIER() asm volatile("s_waitcnt lgkmcnt(0)\n\ts_barrier" ::: "memory")

// One block = 5 waves = one batch element.
// R6: split-M full-K L2 (R5 structure) with fixed h2 delivery: per step each
// L2 wave does ONE ds_read_b32 (lane k = h2[k], stride-1, conflict-free)
// then 50 v_readlane -> SGPR broadcasts feeding v_fmac (SGPR multiplicand).
// R5's 13x ds_read_b128 needed 52 dest VGPRs at a 48-VGPR allocation ->
// compiler serialized into multiple LDS-latency rounds (+610 cy/step).
// One b32 read = one latency, one dest reg, ~6 cy of LDS pipe per wave.
__global__ __launch_bounds__(320, 1) void lstm_fused_kernel(
    const float* __restrict__ x,     // (256,2048,16)
    const float* __restrict__ W1ih,  // (20,16)
    const float* __restrict__ W1hh,  // (20,5)
    const float* __restrict__ b1ih,  // (20)
    const float* __restrict__ b1hh,  // (20)
    const float* __restrict__ W2ih,  // (200,5)
    const float* __restrict__ W2hh,  // (200,50)
    const float* __restrict__ b2ih,  // (200)
    const float* __restrict__ b2hh,  // (200)
    const float* __restrict__ Wfc,   // (20,50)
    const float* __restrict__ bfc,   // (20)
    float* __restrict__ out)         // result(256,20) ++ last(256,50)
{
    const int b    = blockIdx.x;
    const int tid  = threadIdx.x;
    const int lane = tid & 63;
    const int wv   = tid >> 6;

    __shared__ __align__(16) float s_x[2][CHUNK * DIN];   // x dbuf (8 KB)
    __shared__ __align__(16) float s_h1[2][CHUNK][8];     // h1 stream dbuf (4 KB)
    __shared__ __align__(16) float s_h2x[2][64];          // h2 exchange dbuf (512 B)

    const float* xb = x + (size_t)b * TSEQ * DIN;

    if (wv == 4) {
        // ================= wave 4: L1 producer + x stager =================
        const int r1 = (lane < NCLS) ? ((lane & 3) * NH1 + (lane >> 2)) : 0;
        float w1h[NH1], w1x[DIN];
        #pragma unroll
        for (int j = 0; j < NH1; ++j) w1h[j] = W1hh[r1 * NH1 + j];
        #pragma unroll
        for (int d = 0; d < DIN; ++d) w1x[d] = W1ih[r1 * DIN + d];
        const float bias1 = b1ih[r1] + b1hh[r1];
        const bool  isg1  = ((lane & 3) == 2) && (lane < NCLS);
        const float isc1  = isg1 ? 2.f : 1.f;
        const float osc1  = isg1 ? 2.f : 1.f;
        const float off1  = isg1 ? -1.f : 0.f;
        float c1 = 0.f;
        float sh0v = 0.f, sh1v = 0.f, sh2v = 0.f, sh3v = 0.f, sh4v = 0.f;
        float4 xr0, xr1, xr2, xr3;

        auto l1_prod = [&](const float* xs, float* h1out) {
            float4 xv0 = *(const float4*)(xs + 0);
            float4 xv1 = *(const float4*)(xs + 4);
            float4 xv2 = *(const float4*)(xs + 8);
            float4 xv3 = *(const float4*)(xs + 12);
            float sa = fmaf(xv0.y, w1x[1],  xv0.x * w1x[0]);
            sa = fmaf(xv0.z, w1x[2], sa);  sa = fmaf(xv0.w, w1x[3], sa);
            float sb = fmaf(xv1.y, w1x[5],  xv1.x * w1x[4]);
            sb = fmaf(xv1.z, w1x[6], sb);  sb = fmaf(xv1.w, w1x[7], sb);
            float sc = fmaf(xv2.y, w1x[9],  xv2.x * w1x[8]);
            sc = fmaf(xv2.z, w1x[10], sc); sc = fmaf(xv2.w, w1x[11], sc);
            float sd = fmaf(xv3.y, w1x[13], xv3.x * w1x[12]);
            sd = fmaf(xv3.z, w1x[14], sd); sd = fmaf(xv3.w, w1x[15], sd);
            float ha = fmaf(sh1v, w1h[1], sh0v * w1h[0]);
            ha = fmaf(sh2v, w1h[2], ha);
            float hb = fmaf(sh4v, w1h[4], sh3v * w1h[3]);
            float g1 = ((sa + sb) + (sc + sd)) + ((ha + hb) + bias1);
            float act = fmaf(osc1, fast_sigm(isc1 * g1), off1);
            float f_ = qperm<0xB1>(act);
            float gg = qperm<0x4E>(act);
            float o_ = qperm<0x1B>(act);
            c1 = fmaf(f_, c1, act * gg);            // valid on lanes 4j+0
            float h1me = o_ * fast_tanh(c1);
            sh0v = rdlane(h1me, 0);  sh1v = rdlane(h1me, 4);
            sh2v = rdlane(h1me, 8);  sh3v = rdlane(h1me, 12);
            sh4v = rdlane(h1me, 16);
            if ((lane & 3) == 0 && lane < NCLS) h1out[lane >> 2] = h1me;
        };

        // prologue: stage chunk0, run L1 chunk0, stage chunk1, preload chunk2
        xr0 = ((const float4*)(xb))[lane];
        xr1 = ((const float4*)(xb + 256))[lane];
        xr2 = ((const float4*)(xb + 512))[lane];
        xr3 = ((const float4*)(xb + 768))[lane];
        ((float4*)s_x[0])[lane]       = xr0;
        ((float4*)s_x[0])[64 + lane]  = xr1;
        ((float4*)s_x[0])[128 + lane] = xr2;
        ((float4*)s_x[0])[192 + lane] = xr3;
        for (int t = 0; t < CHUNK; ++t)
            l1_prod(&s_x[0][t * DIN], &s_h1[0][t][0]);
        xr0 = ((const float4*)(xb + 1024))[lane];
        xr1 = ((const float4*)(xb + 1280))[lane];
        xr2 = ((const float4*)(xb + 1536))[lane];
        xr3 = ((const float4*)(xb + 1792))[lane];
        ((float4*)s_x[1])[lane]       = xr0;
        ((float4*)s_x[1])[64 + lane]  = xr1;
        ((float4*)s_x[1])[128 + lane] = xr2;
        ((float4*)s_x[1])[192 + lane] = xr3;
        xr0 = ((const float4*)(xb + 2048))[lane];
        xr1 = ((const float4*)(xb + 2304))[lane];
        xr2 = ((const float4*)(xb + 2560))[lane];
        xr3 = ((const float4*)(xb + 2816))[lane];
        W4_BARRIER();                                   // barrier #1

        #pragma unroll 1
        for (int t = 0; t < TSEQ; ++t) {
            const int tt = t & (CHUNK - 1);
            const int c  = t >> 6;
            if (tt == 0 && c + 2 < NCHUNK) {
                // land staged x (chunk c+2) into s_x[c&1]; kick loads for c+3
                ((float4*)s_x[c & 1])[lane]       = xr0;
                ((float4*)s_x[c & 1])[64 + lane]  = xr1;
                ((float4*)s_x[c & 1])[128 + lane] = xr2;
                ((float4*)s_x[c & 1])[192 + lane] = xr3;
                if (c + 3 < NCHUNK) {
                    const float* xc = xb + (size_t)(c + 3) * (CHUNK * DIN);
                    xr0 = ((const float4*)(xc))[lane];
                    xr1 = ((const float4*)(xc + 256))[lane];
                    xr2 = ((const float4*)(xc + 512))[lane];
                    xr3 = ((const float4*)(xc + 768))[lane];
                }
            }
            if (c + 1 < NCHUNK)
                l1_prod(&s_x[(c & 1) ^ 1][tt * DIN], &s_h1[(c & 1) ^ 1][tt][0]);
            W4_BARRIER();
        }
    } else {
        // ================= waves 0-3: split-M full-K L2 ==================
        const int  ul   = lane >> 2;
        const int  g    = lane & 3;
        const int  uoff = (wv < 3) ? 13 * wv : 38;      // {0,13,26,38}
        const int  ucnt = (wv < 2) ? 13 : 12;           // {13,13,12,12}
        const bool on   = (ul < ucnt);
        const int  u    = uoff + (on ? ul : 0);
        const int  rr   = g * NH2 + u;                  // my gate row

        float w2h[NH2];                                 // full-K recurrent weights
        #pragma unroll
        for (int k = 0; k < NH2; ++k) w2h[k] = on ? W2hh[rr * NH2 + k] : 0.f;
        float w2i[NH1];
        float bias2 = 0.f;
        if (on) {
            #pragma unroll
            for (int d = 0; d < NH1; ++d) w2i[d] = W2ih[rr * NH1 + d];
            bias2 = b2ih[rr] + b2hh[rr];
        } else {
            #pragma unroll
            for (int d = 0; d < NH1; ++d) w2i[d] = 0.f;
        }
        const bool  isg2 = (g == 2);
        const float isc2 = isg2 ? 2.f : 1.f;
        const float osc2 = isg2 ? 2.f : 1.f;
        const float off2 = isg2 ? -1.f : 0.f;

        float c2 = 0.f;
        if (wv == 0) { s_h2x[0][lane] = 0.f; s_h2x[1][lane] = 0.f; }
        __syncthreads();                                // barrier #1

        // prefetch h1(t=0) into carried regs (off the critical chain)
        float4 h1r4 = *(const float4*)&s_h1[0][0][0];
        float  h1r1 = s_h1[0][0][4];

        #pragma unroll 1
        for (int t = 0; t < TSEQ; ++t) {
            const int rsl = (t + 1) & 1;                // h2(t-1) slot
            const int wsl = t & 1;                      // h2(t) slot

            // ONE per-lane exchange read: lane k holds h2[k] (stride-1,
            // 2-way bank aliasing = free). Single LDS latency on the chain.
            float h2v = s_h2x[rsl][lane];

            // x-side gate from h1 regs carried since LAST step (data long
            // arrived; runs under the ds_read latency)
            float xq = fmaf(h1r4.x, w2i[0], bias2);
            xq = fmaf(h1r4.y, w2i[1], xq);
            xq = fmaf(h1r4.z, w2i[2], xq);
            xq = fmaf(h1r4.w, w2i[3], xq);
            xq = fmaf(h1r1,  w2i[4], xq);

            // issue h1 reads for t+1 (latency spans the whole chain + barrier)
            {
                const int tn = (t + 1) & (TSEQ - 1);    // t=2047: stale, unused
                const int sl = (tn >> 6) & 1, ix = tn & (CHUNK - 1);
                h1r4 = *(const float4*)&s_h1[sl][ix][0];
                h1r1 = s_h1[sl][ix][4];
            }

            // full-K matvec: readlane->SGPR broadcast feeding v_fmac.
            // Accumulation order identical to R5 (4 accs, k === j mod 4).
            float a0 = 0.f, a1 = 0.f, a2 = 0.f, a3 = 0.f;
            #pragma unroll
            for (int k = 0; k < 48; k += 4) {
                a0 = fmaf(rdlane(h2v, k + 0), w2h[k + 0], a0);
                a1 = fmaf(rdlane(h2v, k + 1), w2h[k + 1], a1);
                a2 = fmaf(rdlane(h2v, k + 2), w2h[k + 2], a2);
                a3 = fmaf(rdlane(h2v, k + 3), w2h[k + 3], a3);
            }
            a0 = fmaf(rdlane(h2v, 48), w2h[48], a0);
            a1 = fmaf(rdlane(h2v, 49), w2h[49], a1);

            float pre  = ((a0 + a1) + (a2 + a3)) + xq;
            float act2 = fmaf(osc2, fast_sigm(isc2 * pre), off2);
            float v1 = qperm<0xB1>(act2);
            float v2 = qperm<0x4E>(act2);
            float v3 = qperm<0x1B>(act2);
            c2 = fmaf(v1, c2, act2 * v2);               // valid on g==0 lanes
            float hn = v3 * fast_tanh(c2);
            if (g == 0 && on) s_h2x[wsl][u] = hn;
            __syncthreads();
        }
    }

    __syncthreads();                                    // join (count-matched)
    // ---- outputs: result(256,20) @0, last(256,50) @5120 ----
    // final h2 = step 2047 -> slot 1
    if (tid < NH2) out[BATCH * NCLS + b * NH2 + tid] = s_h2x[1][tid];
    if (tid < NCLS) {
        float acc = bfc[tid];
        const float* wr = Wfc + tid * NH2;
        #pragma unroll
        for (int j = 0; j < NH2; ++j) acc = fmaf(s_h2x[1][j], wr[j], acc);
        out[b * NCLS + tid] = acc;
    }
}

} // namespace

extern "C" void kernel_launch(void* const* d_in, const int* in_sizes, int n_in,
                              void* d_out, int out_size, void* d_ws, size_t ws_size,
                              hipStream_t stream) {
    (void)in_sizes; (void)n_in; (void)d_ws; (void)ws_size; (void)out_size;
    const float* x    = (const float*)d_in[0];
    const float* W1ih = (const float*)d_in[1];
    const float* W1hh = (const float*)d_in[2];
    const float* b1ih = (const float*)d_in[3];
    const float* b1hh = (const float*)d_in[4];
    const float* W2ih = (const float*)d_in[5];
    const float* W2hh = (const float*)d_in[6];
    const float* b2ih = (const float*)d_in[7];
    const float* b2hh = (const float*)d_in[8];
    const float* Wfc  = (const float*)d_in[9];
    const float* bfc  = (const float*)d_in[10];

    lstm_fused_kernel<<<dim3(BATCH), dim3(320), 0, stream>>>(
        x, W1ih, W1hh, b1ih, b1hh, W2ih, W2hh, b2ih, b2hh, Wfc, bfc,
        (float*)d_out);
}